// Round 18
// baseline (47.152 us; speedup 1.0000x reference)
//
#include <hip/hip_runtime.h>

#define NCH 8
#define CACHE 8   // float4 per lane -> covers segments up to 256 points per frustum

typedef float v4f __attribute__((ext_vector_type(4)));

// Wave-cooperative lower_bound: smallest idx with a[idx] >= key. 4 memory rounds for n=2M.
__device__ __forceinline__ int wave_lower_bound(const int* __restrict__ a, int n, int key,
                                                int lane) {
    int lo = 0, len = n;
    while (len > 64) {
        int step = (len + 63) >> 6;                       // ceil(len/64)
        int p = lo + lane * step;
        int v = (p < lo + len) ? a[p] : 0x7fffffff;
        unsigned long long bal = __ballot(v < key);
        int cnt = __popcll(bal);                          // preds form a prefix (sorted)
        if (cnt == 0) return lo;
        int nlo = lo + (cnt - 1) * step + 1;
        int nhi = lo + len;
        int cap = lo + cnt * step;
        if (cnt < 64 && cap < nhi) nhi = cap;
        lo = nlo; len = nhi - nlo;
    }
    int v = (lane < len) ? a[lo + lane] : 0x7fffffff;
    unsigned long long bal = __ballot(v < key);
    return lo + __popcll(bal);
}

// Phase 1: wave-per-frustum stats only (search + clamped batch load + shuffle reduce).
// No normalize/store phase -> short wave lifetime; leaves pc L3-resident for phase 2.
__global__ __launch_bounds__(128) void k_stats2(
    const float* __restrict__ pc, const int* __restrict__ i_frustum,
    const float* __restrict__ counts, int n, int F,
    float* __restrict__ out_mean, float* __restrict__ out_std,
    float* __restrict__ out_max)
{
    const int wid = (blockIdx.x * blockDim.x + threadIdx.x) >> 6;  // global wave id
    if (wid >= F) return;                                          // wave-uniform exit
    const int lane = threadIdx.x & 63;

    const int s = wave_lower_bound(i_frustum, n, wid, lane);
    const float cnt = counts[wid];
    const int e = s + (int)cnt;      // counts are small integers, exact in float

    const float4* __restrict__ pc4 = reinterpret_cast<const float4*>(pc);
    const int b = s * 2, E = e * 2;  // float4-granular (NCH=8 -> 2 float4/point)
    const int lim = max(E - 1, 0);

    float4 sum = {0.f, 0.f, 0.f, 0.f};
    float4 sq  = {0.f, 0.f, 0.f, 0.f};
    float4 mx  = {0.f, 0.f, 0.f, 0.f};  // 0-init == scatter-max onto zeros (include_self)
    float4 c[CACHE];

    // Unconditional clamped loads -> all 8 issue back-to-back.
    {
        int k = b + lane;
        #pragma unroll
        for (int u = 0; u < CACHE; ++u) {
            c[u] = pc4[min(k, lim)];
            k += 64;
        }
    }
    // Branchless masked accumulate (0 is identity for sum/sq and max-vs-0 semantics).
    {
        int k = b + lane;
        #pragma unroll
        for (int u = 0; u < CACHE; ++u) {
            const bool in = k < E;
            float vx = in ? c[u].x : 0.f, vy = in ? c[u].y : 0.f;
            float vz = in ? c[u].z : 0.f, vw = in ? c[u].w : 0.f;
            sum.x += vx; sq.x += vx * vx; mx.x = fmaxf(mx.x, vx);
            sum.y += vy; sq.y += vy * vy; mx.y = fmaxf(mx.y, vy);
            sum.z += vz; sq.z += vz * vz; mx.z = fmaxf(mx.z, vz);
            sum.w += vw; sq.w += vw * vw; mx.w = fmaxf(mx.w, vw);
            k += 64;
        }
        for (int kk = b + lane + CACHE * 64; kk < E; kk += 64) {  // rare overflow
            float4 v = pc4[kk];
            sum.x += v.x; sq.x += v.x * v.x; mx.x = fmaxf(mx.x, v.x);
            sum.y += v.y; sq.y += v.y * v.y; mx.y = fmaxf(mx.y, v.y);
            sum.z += v.z; sq.z += v.z * v.z; mx.z = fmaxf(mx.z, v.z);
            sum.w += v.w; sq.w += v.w * v.w; mx.w = fmaxf(mx.w, v.w);
        }
    }

    // Lane parity p = lane&1 owns channels [4p, 4p+4). Reduce lanes differing in bits 1..5.
    #pragma unroll
    for (int m = 2; m <= 32; m <<= 1) {
        sum.x += __shfl_xor(sum.x, m, 64);
        sum.y += __shfl_xor(sum.y, m, 64);
        sum.z += __shfl_xor(sum.z, m, 64);
        sum.w += __shfl_xor(sum.w, m, 64);
        sq.x  += __shfl_xor(sq.x,  m, 64);
        sq.y  += __shfl_xor(sq.y,  m, 64);
        sq.z  += __shfl_xor(sq.z,  m, 64);
        sq.w  += __shfl_xor(sq.w,  m, 64);
        mx.x = fmaxf(mx.x, __shfl_xor(mx.x, m, 64));
        mx.y = fmaxf(mx.y, __shfl_xor(mx.y, m, 64));
        mx.z = fmaxf(mx.z, __shfl_xor(mx.z, m, 64));
        mx.w = fmaxf(mx.w, __shfl_xor(mx.w, m, 64));
    }

    if (lane < 2) {  // lane 0 -> channels 0-3, lane 1 -> channels 4-7
        const float invc = 1.0f / fmaxf(cnt, 1.0f);
        float4 mean, sd;
        mean.x = sum.x * invc; mean.y = sum.y * invc;
        mean.z = sum.z * invc; mean.w = sum.w * invc;
        float vx = fmaxf(sq.x * invc - mean.x * mean.x, 0.0f);
        float vy = fmaxf(sq.y * invc - mean.y * mean.y, 0.0f);
        float vz = fmaxf(sq.z * invc - mean.z * mean.z, 0.0f);
        float vw = fmaxf(sq.w * invc - mean.w * mean.w, 0.0f);
        sd.x = sqrtf(vx); sd.y = sqrtf(vy); sd.z = sqrtf(vz); sd.w = sqrtf(vw);
        reinterpret_cast<float4*>(out_mean + (size_t)wid * NCH)[lane] = mean;
        reinterpret_cast<float4*>(out_std  + (size_t)wid * NCH)[lane] = sd;
        reinterpret_cast<float4*>(out_max  + (size_t)wid * NCH)[lane] = mx;
    }
}

// Phase 2: pure streaming normalize, one thread per float4 (fill-kernel shape).
// f = i_frustum[i] (i_inv identity); mean/std gathers are L1/L2-hot (460 KB);
// pc read is L3-resident after phase 1; NT stores for the never-re-read output.
__global__ __launch_bounds__(256) void k_norm2(
    const float* __restrict__ pc, const int* __restrict__ i_frustum,
    const float* __restrict__ meanb, const float* __restrict__ stdb,
    float* __restrict__ out_pcn, int n4)
{
    const int t = blockIdx.x * blockDim.x + threadIdx.x;
    if (t >= n4) return;
    const int i = t >> 1, half = t & 1;
    const int f = i_frustum[i];

    const float4 m = reinterpret_cast<const float4*>(meanb + (size_t)f * NCH)[half];
    const float4 sd = reinterpret_cast<const float4*>(stdb + (size_t)f * NCH)[half];
    const float4 p = reinterpret_cast<const float4*>(pc)[t];

    v4f o;
    o.x = (p.x - m.x) / (sd.x > 0.f ? sd.x : 1.f);
    o.y = (p.y - m.y) / (sd.y > 0.f ? sd.y : 1.f);
    o.z = (p.z - m.z) / (sd.z > 0.f ? sd.z : 1.f);
    o.w = (p.w - m.w) / (sd.w > 0.f ? sd.w : 1.f);
    __builtin_nontemporal_store(o, &reinterpret_cast<v4f*>(out_pcn)[t]);
}

extern "C" void kernel_launch(void* const* d_in, const int* in_sizes, int n_in,
                              void* d_out, int out_size, void* d_ws, size_t ws_size,
                              hipStream_t stream) {
    const float* pc        = (const float*)d_in[0];
    const int*   i_frustum = (const int*)d_in[1];
    const float* counts    = (const float*)d_in[3];

    int n = in_sizes[0] / NCH;   // 2,000,000 points
    int F = in_sizes[3];         // 14,400 frustums

    float* out_mean = (float*)d_out;
    float* out_std  = out_mean + (size_t)F * NCH;
    float* out_max  = out_std  + (size_t)F * NCH;
    float* out_pcn  = out_max  + (size_t)F * NCH;

    int waves_per_block = 128 / 64;
    int blocks = (F + waves_per_block - 1) / waves_per_block;
    k_stats2<<<blocks, 128, 0, stream>>>(pc, i_frustum, counts, n, F,
                                         out_mean, out_std, out_max);

    int n4 = n * 2;
    int nblocks = (n4 + 255) / 256;
    k_norm2<<<nblocks, 256, 0, stream>>>(pc, i_frustum, out_mean, out_std, out_pcn, n4);
}

// Round 19
// 29.360 us; speedup vs baseline: 1.6060x; 1.6060x over previous
//
#include <hip/hip_runtime.h>

#define NCH 8
#define CACHE 6   // float4 per lane -> 384 slots; covers segments up to 192 points (max ~190)

typedef float v4f __attribute__((ext_vector_type(4)));

__device__ __forceinline__ v4f norm4(const float4& v, const float4& m, const float4& d) {
    v4f o;
    o.x = (v.x - m.x) * d.x;
    o.y = (v.y - m.y) * d.y;
    o.z = (v.z - m.z) * d.z;
    o.w = (v.w - m.w) * d.w;
    return o;
}

// Wave-cooperative lower_bound: smallest idx with a[idx] >= key. 4 memory rounds for n=2M.
__device__ __forceinline__ int wave_lower_bound(const int* __restrict__ a, int n, int key,
                                                int lane) {
    int lo = 0, len = n;
    while (len > 64) {
        int step = (len + 63) >> 6;                       // ceil(len/64)
        int p = lo + lane * step;
        int v = (p < lo + len) ? a[p] : 0x7fffffff;
        unsigned long long bal = __ballot(v < key);
        int cnt = __popcll(bal);                          // preds form a prefix (sorted)
        if (cnt == 0) return lo;
        int nlo = lo + (cnt - 1) * step + 1;
        int nhi = lo + len;
        int cap = lo + cnt * step;
        if (cnt < 64 && cap < nhi) nhi = cap;
        lo = nlo; len = nhi - nlo;
    }
    int v = (lane < len) ? a[lo + lane] : 0x7fffffff;
    unsigned long long bal = __ballot(v < key);
    return lo + __popcll(bal);
}

// One WAVE per frustum, fused search+stats+normalize (R17 structure).
// Round-19 deltas: CACHE=6 (384 slots vs 512 -> less clamped-load waste),
// 256-thread blocks (4 waves/block -> coarser dispatch granules, faster ramp).
__global__ __launch_bounds__(256) void k_fused(
    const float* __restrict__ pc, const int* __restrict__ i_frustum,
    const float* __restrict__ counts, int n, int F,
    float* __restrict__ out_mean, float* __restrict__ out_std,
    float* __restrict__ out_max, float* __restrict__ out_pcn)
{
    const int wid = (blockIdx.x * blockDim.x + threadIdx.x) >> 6;  // global wave id
    if (wid >= F) return;                                          // wave-uniform exit
    const int lane = threadIdx.x & 63;

    const int s = wave_lower_bound(i_frustum, n, wid, lane);
    const float cnt = counts[wid];
    const int e = s + (int)cnt;      // counts are small integers, exact in float

    const float4* __restrict__ pc4 = reinterpret_cast<const float4*>(pc);
    v4f* __restrict__ out4 = reinterpret_cast<v4f*>(out_pcn);

    const int b = s * 2, E = e * 2;  // float4-granular range (NCH=8 -> 2 float4/point)
    const int lim = max(E - 1, 0);   // clamp target (empty segment -> index 0, masked off)

    float4 sum = {0.f, 0.f, 0.f, 0.f};
    float4 sq  = {0.f, 0.f, 0.f, 0.f};
    float4 mx  = {0.f, 0.f, 0.f, 0.f};  // 0-init == scatter-max onto zeros (include_self)
    float4 c[CACHE];

    // Phase 1: unconditional clamped loads -> all issue back-to-back.
    {
        int k = b + lane;
        #pragma unroll
        for (int u = 0; u < CACHE; ++u) {
            c[u] = pc4[min(k, lim)];
            k += 64;
        }
    }
    // Phase 2: branchless masked accumulate (0 = identity for sum/sq and max-vs-0).
    {
        int k = b + lane;
        #pragma unroll
        for (int u = 0; u < CACHE; ++u) {
            const bool in = k < E;
            float vx = in ? c[u].x : 0.f, vy = in ? c[u].y : 0.f;
            float vz = in ? c[u].z : 0.f, vw = in ? c[u].w : 0.f;
            sum.x += vx; sq.x += vx * vx; mx.x = fmaxf(mx.x, vx);
            sum.y += vy; sq.y += vy * vy; mx.y = fmaxf(mx.y, vy);
            sum.z += vz; sq.z += vz * vz; mx.z = fmaxf(mx.z, vz);
            sum.w += vw; sq.w += vw * vw; mx.w = fmaxf(mx.w, vw);
            k += 64;
        }
        for (int kk = b + lane + CACHE * 64; kk < E; kk += 64) {  // tail (segments > 192 pts)
            float4 v = pc4[kk];
            sum.x += v.x; sq.x += v.x * v.x; mx.x = fmaxf(mx.x, v.x);
            sum.y += v.y; sq.y += v.y * v.y; mx.y = fmaxf(mx.y, v.y);
            sum.z += v.z; sq.z += v.z * v.z; mx.z = fmaxf(mx.z, v.z);
            sum.w += v.w; sq.w += v.w * v.w; mx.w = fmaxf(mx.w, v.w);
        }
    }

    // Lane parity p = lane&1 owns channels [4p, 4p+4). Reduce lanes differing in bits 1..5.
    #pragma unroll
    for (int m = 2; m <= 32; m <<= 1) {
        sum.x += __shfl_xor(sum.x, m, 64);
        sum.y += __shfl_xor(sum.y, m, 64);
        sum.z += __shfl_xor(sum.z, m, 64);
        sum.w += __shfl_xor(sum.w, m, 64);
        sq.x  += __shfl_xor(sq.x,  m, 64);
        sq.y  += __shfl_xor(sq.y,  m, 64);
        sq.z  += __shfl_xor(sq.z,  m, 64);
        sq.w  += __shfl_xor(sq.w,  m, 64);
        mx.x = fmaxf(mx.x, __shfl_xor(mx.x, m, 64));
        mx.y = fmaxf(mx.y, __shfl_xor(mx.y, m, 64));
        mx.z = fmaxf(mx.z, __shfl_xor(mx.z, m, 64));
        mx.w = fmaxf(mx.w, __shfl_xor(mx.w, m, 64));
    }

    // Every lane holds its parity-group totals; compute stats redundantly (cheap).
    const float invc = 1.0f / fmaxf(cnt, 1.0f);
    float4 mean, sd, dv;
    mean.x = sum.x * invc; mean.y = sum.y * invc; mean.z = sum.z * invc; mean.w = sum.w * invc;
    float vx = fmaxf(sq.x * invc - mean.x * mean.x, 0.0f);
    float vy = fmaxf(sq.y * invc - mean.y * mean.y, 0.0f);
    float vz = fmaxf(sq.z * invc - mean.z * mean.z, 0.0f);
    float vw = fmaxf(sq.w * invc - mean.w * mean.w, 0.0f);
    sd.x = sqrtf(vx); sd.y = sqrtf(vy); sd.z = sqrtf(vz); sd.w = sqrtf(vw);
    dv.x = 1.0f / (sd.x > 0.f ? sd.x : 1.f);
    dv.y = 1.0f / (sd.y > 0.f ? sd.y : 1.f);
    dv.z = 1.0f / (sd.z > 0.f ? sd.z : 1.f);
    dv.w = 1.0f / (sd.w > 0.f ? sd.w : 1.f);

    if (lane < 2) {  // lane 0 -> channels 0-3, lane 1 -> channels 4-7
        reinterpret_cast<float4*>(out_mean + (size_t)wid * NCH)[lane] = mean;
        reinterpret_cast<float4*>(out_std  + (size_t)wid * NCH)[lane] = sd;
        reinterpret_cast<float4*>(out_max  + (size_t)wid * NCH)[lane] = mx;
    }

    // Normalize from the register cache; NT stores (output never re-read).
    {
        int k = b + lane;
        #pragma unroll
        for (int u = 0; u < CACHE; ++u) {
            if (k < E) {
                v4f o = norm4(c[u], mean, dv);
                __builtin_nontemporal_store(o, &out4[k]);
            }
            k += 64;
        }
        for (int kk = b + lane + CACHE * 64; kk < E; kk += 64) {  // tail
            v4f o = norm4(pc4[kk], mean, dv);
            __builtin_nontemporal_store(o, &out4[kk]);
        }
    }
}

extern "C" void kernel_launch(void* const* d_in, const int* in_sizes, int n_in,
                              void* d_out, int out_size, void* d_ws, size_t ws_size,
                              hipStream_t stream) {
    const float* pc        = (const float*)d_in[0];
    const int*   i_frustum = (const int*)d_in[1];
    const float* counts    = (const float*)d_in[3];

    int n = in_sizes[0] / NCH;   // 2,000,000 points
    int F = in_sizes[3];         // 14,400 frustums

    float* out_mean = (float*)d_out;
    float* out_std  = out_mean + (size_t)F * NCH;
    float* out_max  = out_std  + (size_t)F * NCH;
    float* out_pcn  = out_max  + (size_t)F * NCH;

    int waves_per_block = 256 / 64;
    int blocks = (F + waves_per_block - 1) / waves_per_block;
    k_fused<<<blocks, 256, 0, stream>>>(pc, i_frustum, counts, n, F,
                                        out_mean, out_std, out_max, out_pcn);
}